// Round 8
// baseline (540.797 us; speedup 1.0000x reference)
//
#include <hip/hip_runtime.h>
#include <hip/hip_bf16.h>
#include <math.h>

#define N_NODES 51200
#define N_EDGES 614400
#define N_GRAPHS 256
#define T_CAPS 8
#define D_DIM 128
#define BN_EPS 1e-5f
#define MAXC 512      // max nodes/graph (mean 200, sd ~14; 512 is >20 sd)
#define NTHR 1024
#define GSTRIDE (N_GRAPHS * NTHR)  // 262144 threads total

__device__ inline float waveReduceSum(float v) {
#pragma unroll
  for (int off = 1; off < 64; off <<= 1) v += __shfl_xor(v, off, 64);
  return v;
}
__device__ inline float bf_lo(unsigned u) { return __uint_as_float(u << 16); }
__device__ inline float bf_hi(unsigned u) { return __uint_as_float(u & 0xffff0000u); }

// device-scope grid barrier. Grid (256 blk x 1024 thr) <= HW capacity (>=1 blk/CU
// on 256 CUs even at worst-case packing), so all blocks are co-resident.
// Release fence writes back per-XCD L2; acquire fence invalidates L1/L2 so
// post-barrier loads see other XCDs' data.
__device__ inline void grid_bar(int* bar, int phase) {
  __syncthreads();
  if (threadIdx.x == 0) {
    __threadfence();  // release: L2 writeback to coherence point
    __hip_atomic_fetch_add(&bar[phase], 1, __ATOMIC_RELEASE, __HIP_MEMORY_SCOPE_AGENT);
    while (__hip_atomic_load(&bar[phase], __ATOMIC_ACQUIRE, __HIP_MEMORY_SCOPE_AGENT) <
           (int)gridDim.x)
      __builtin_amdgcn_s_sleep(2);
    __threadfence();  // acquire: invalidate L1/L2
  }
  __syncthreads();
}

__global__ void __launch_bounds__(NTHR) mega(
    const float* __restrict__ x, const float* __restrict__ ew,
    const float* __restrict__ gamma, const float* __restrict__ beta,
    const float* __restrict__ W, const float* __restrict__ bias,
    const int* __restrict__ row, const int* __restrict__ col,
    const int* __restrict__ batch, int* cnt_in, int* cursor, int* start, int* node_start,
    int* bsum, float* scale, float* shift, float* dis, float* rawxsum, float* rawxsq,
    float* WT, int2* csr, __hip_bfloat162* y, unsigned* agg_bf, float* out, int* bar) {
  int bid = blockIdx.x, tid = threadIdx.x;
  int gtid = bid * NTHR + tid;

  __shared__ float smem[7424];  // 29 KB arena, aliased per phase

  // ---- P0: zero counters, graph bounds from sorted batch, W transpose ----
  if (gtid < N_NODES) {
    cnt_in[gtid] = 0;
    cursor[gtid] = 0;
    int bn = batch[gtid];
    if (gtid == 0) {
      for (int g = 0; g <= bn; g++) start[g] = 0;
    } else {
      int bp = batch[gtid - 1];
      for (int g = bp + 1; g <= bn; g++) start[g] = gtid;
    }
    if (gtid == N_NODES - 1)
      for (int g = bn + 1; g <= N_GRAPHS; g++) start[g] = N_NODES;
  }
  if (gtid < T_CAPS * D_DIM * D_DIM) {  // coalesced read, scattered write
    int t = gtid >> 14, r = gtid & 16383;
    int o = r >> 7, oo = r & 127;
    WT[(t << 14) + (oo << 7) + o] = W[gtid];
  }
  grid_bar(bar, 0);

  // ---- P1: edge in-degree histogram + per-graph x stats ----
  for (int e = gtid; e < N_EDGES; e += GSTRIDE) atomicAdd(&cnt_in[col[e]], 1);
  {
    int d = tid & 127, h = tid >> 7;  // 8-way over rows
    int st = start[bid], en = start[bid + 1];
    float s = 0.f, s2 = 0.f;
    for (int n = st + h; n < en; n += 8) {
      float v = x[n * D_DIM + d];
      s += v;
      s2 += v * v;
    }
    float* ls = smem;           // 1024
    float* ls2 = smem + 1024;   // 1024
    ls[tid] = s;
    ls2[tid] = s2;
    __syncthreads();
    if (h == 0) {
      float a = 0.f, b2 = 0.f;
#pragma unroll
      for (int k = 0; k < 8; k++) {
        a += ls[k * 128 + d];
        b2 += ls2[k * 128 + d];
      }
      rawxsum[bid * D_DIM + d] = a;
      rawxsq[bid * D_DIM + d] = b2;
    }
  }
  grid_bar(bar, 1);

  // ---- P2: per-block chunk sums of cnt_in (256 x 200) + finalize BN ----
  {
    int* li = (int*)smem;
    if (tid < 256) li[tid] = (tid < 200) ? cnt_in[bid * 200 + tid] : 0;
    __syncthreads();
    for (int off = 128; off; off >>= 1) {
      if (tid < off) li[tid] += li[tid + off];
      __syncthreads();
    }
    if (tid == 0) bsum[bid] = li[0];
    __syncthreads();
    if (bid < D_DIM) {  // blocks 0..127: feature bid BN reduction over graphs
      float* ls = smem;
      float* ls2 = smem + 256;
      if (tid < 256) {
        ls[tid] = rawxsum[tid * D_DIM + bid];
        ls2[tid] = rawxsq[tid * D_DIM + bid];
      }
      __syncthreads();
      for (int off = 128; off; off >>= 1) {
        if (tid < off) {
          ls[tid] += ls[tid + off];
          ls2[tid] += ls2[tid + off];
        }
        __syncthreads();
      }
      if (tid == 0) {
        float mu = ls[0] * (1.0f / N_NODES);
        float var = ls2[0] * (1.0f / N_NODES) - mu * mu;
        float rstd = rsqrtf(var + BN_EPS);
        float sc = gamma[bid] * rstd;
        scale[bid] = sc;
        shift[bid] = beta[bid] - mu * sc;
      }
    }
  }
  grid_bar(bar, 2);

  // ---- P3: node_start = global exclusive scan of cnt_in ----
  {
    int* li = (int*)smem;
    if (tid < 256) li[tid] = (tid < bid) ? bsum[tid] : 0;
    __syncthreads();
    for (int off = 128; off; off >>= 1) {
      if (tid < off) li[tid] += li[tid + off];
      __syncthreads();
    }
    int base = li[0];
    __syncthreads();
    int v = (tid < 200) ? cnt_in[bid * 200 + tid] : 0;
    if (tid < 256) li[tid] = v;
    __syncthreads();
    for (int off = 1; off < 256; off <<= 1) {
      int u = (tid < 256 && tid >= off) ? li[tid - off] : 0;
      __syncthreads();
      if (tid < 256) li[tid] += u;
      __syncthreads();
    }
    if (tid < 200) node_start[bid * 200 + tid] = base + li[tid] - v;
  }
  grid_bar(bar, 3);

  // ---- P4: bucket edges by destination ----
  for (int e = gtid; e < N_EDGES; e += GSTRIDE) {
    int c = col[e];
    int slot = node_start[c] + atomicAdd(&cursor[c], 1);
    csr[slot] = make_int2(row[e], __float_as_int(ew[e]));
  }
  grid_bar(bar, 4);

  // ---- P5: deg from csr, dis = rsqrt(deg+1), y = bf16(dis*xhat) ----
  int wid = gtid >> 6, lane = tid & 63;
  for (int n = wid; n < N_NODES; n += GSTRIDE / 64) {
    int st = node_start[n], c = cnt_in[n];
    float s = 0.f;
    for (int k = lane; k < c; k += 64) s += __int_as_float(csr[st + k].y);
    s = waveReduceSum(s);
    float dv = s + 1.0f;  // + self-loop
    float dn = dv > 0.f ? rsqrtf(fmaxf(dv, 1e-12f)) : 0.f;
    if (lane == 0) dis[n] = dn;
    float2 scv = ((const float2*)scale)[lane];
    float2 shv = ((const float2*)shift)[lane];
    float2 xv = ((const float2*)x)[n * 64 + lane];
    float2 yv;
    yv.x = dn * (xv.x * scv.x + shv.x);
    yv.y = dn * (xv.y * scv.y + shv.y);
    y[n * 64 + lane] = __float22bfloat162_rn(yv);
  }
  grid_bar(bar, 5);

  // ---- P6: agg[n] = bf16( dis[n] * (y[n] + sum_e ew_e*y[src_e]) ) ----
  for (int n = wid; n < N_NODES; n += GSTRIDE / 64) {
    int st = node_start[n], c = cnt_in[n];
    float2 a = __bfloat1622float2(y[n * 64 + lane]);
    int j = 0;
    for (; j + 4 <= c; j += 4) {
      int2 e0 = csr[st + j], e1 = csr[st + j + 1], e2 = csr[st + j + 2], e3 = csr[st + j + 3];
      float2 v0 = __bfloat1622float2(y[e0.x * 64 + lane]);
      float2 v1 = __bfloat1622float2(y[e1.x * 64 + lane]);
      float2 v2 = __bfloat1622float2(y[e2.x * 64 + lane]);
      float2 v3 = __bfloat1622float2(y[e3.x * 64 + lane]);
      float w0 = __int_as_float(e0.y), w1 = __int_as_float(e1.y);
      float w2 = __int_as_float(e2.y), w3 = __int_as_float(e3.y);
      a.x += w0 * v0.x + w1 * v1.x + w2 * v2.x + w3 * v3.x;
      a.y += w0 * v0.y + w1 * v1.y + w2 * v2.y + w3 * v3.y;
    }
    for (; j < c; j++) {
      int2 e = csr[st + j];
      float2 v = __bfloat1622float2(y[e.x * 64 + lane]);
      float w = __int_as_float(e.y);
      a.x += w * v.x;
      a.y += w * v.y;
    }
    float dn = dis[n];
    a.x *= dn;
    a.y *= dn;
    agg_bf[n * 64 + lane] = *(unsigned*)&(__hip_bfloat162&)*(
        __hip_bfloat162[]){__float22bfloat162_rn(a)};
  }
  grid_bar(bar, 6);

  // ---- P7: routing (per-graph g = bid), v3 structure ----
  {
    int g = bid;
    int st = start[g], c = start[g + 1] - st;
    float(*dt_sh)[T_CAPS] = (float(*)[T_CAPS])smem;            // [512][8]
    float(*ac_sh)[D_DIM] = (float(*)[D_DIM])(smem + 4096);     // [8][128]
    float(*s_sh)[D_DIM] = (float(*)[D_DIM])(smem + 5120);      // [8][128]
    float(*wv_sh)[132] = (float(*)[132])(smem + 6144);         // [8][132]
    float* csum_sh = smem + 7200;
    float* bv_sh = smem + 7208;
    float* f_sh = smem + 7216;
    float(*s2p)[2] = (float(*)[2])(smem + 7224);
    float* csp_sh = smem + 7240;  // 32
    float* scratch = smem;        // aliases dt region when dt dead
    const uint2* aggb2 = (const uint2*)agg_bf;
    const uint4* aggb4 = (const uint4*)agg_bf;

    for (int i = tid; i < T_CAPS * 132; i += NTHR) (&wv_sh[0][0])[i] = 0.f;
    if (tid < T_CAPS) {
      bv_sh[tid] = 0.f;
      csum_sh[tid] = 0.125f * (float)c;
    }
    {
      int d2 = tid & 63, h = tid >> 6;  // 16-way over nodes
      float sx = 0.f, sy = 0.f;
      for (int n = st + h; n < st + c; n += 16) {
        unsigned u = agg_bf[n * 64 + d2];
        sx += bf_lo(u);
        sy += bf_hi(u);
      }
      scratch[h * 128 + d2 * 2] = sx;
      scratch[h * 128 + d2 * 2 + 1] = sy;
    }
    __syncthreads();
    if (tid < 128) {
      float s = 0.f;
#pragma unroll
      for (int h = 0; h < 16; h++) s += scratch[h * 128 + tid];
      s *= 0.125f;
#pragma unroll
      for (int t = 0; t < T_CAPS; t++) ac_sh[t][tid] = s;
    }
    __syncthreads();

    int tG = tid >> 7, oG = tid & 127;
    int nL = tid >> 3, tL = tid & 7;
    int tA = tid >> 7, rep = (tid >> 5) & 3, l32 = tid & 31;

    for (int iter = 0; iter < 3; iter++) {
      {  // GEMV1
        const float* Wt = W + (tG << 14);
        float s = 0.f;
#pragma unroll 8
        for (int dd = 0; dd < D_DIM; dd++) s += ac_sh[tG][dd] * Wt[dd * D_DIM + oG];
        s += csum_sh[tG] * bias[tG * D_DIM + oG];
        if (iter == 2) {
          float cf = (float)c;
          float ic = 1.0f / fmaxf(cf, 1.0f);
          s += (scale[oG] * rawxsum[g * D_DIM + oG] + cf * shift[oG]) * ic;
        }
        s_sh[tG][oG] = s;
        float p = waveReduceSum(s * s);
        if ((tid & 63) == 0) s2p[tG][(tid >> 6) & 1] = p;
      }
      __syncthreads();
      if (tid < T_CAPS) {
        float s2 = s2p[tid][0] + s2p[tid][1];
        float f = (s2 / (1.0f + s2)) * rsqrtf(s2 + 1e-16f);
        f_sh[tid] = f;
        if (iter == 2) out[g * T_CAPS + tid] = sqrtf(f * f * s2 + 1e-16f);
      }
      __syncthreads();
      if (iter == 2) return;
      s_sh[tG][oG] *= f_sh[tG];
      __syncthreads();
      {  // GEMV2 (running wv/bv)
        const float* WTt = WT + (tG << 14);
        float s = 0.f;
#pragma unroll 8
        for (int oo = 0; oo < D_DIM; oo++) s += s_sh[tG][oo] * WTt[oo * D_DIM + oG];
        wv_sh[tG][oG] += s;
        float bp = bias[tG * D_DIM + oG] * s_sh[tG][oG];
        bp = waveReduceSum(bp);
        if ((tid & 63) == 0) s2p[tG][(tid >> 6) & 1] = bp;
      }
      __syncthreads();
      if (tid < T_CAPS) bv_sh[tid] += s2p[tid][0] + s2p[tid][1];
      __syncthreads();

      float4 acc = make_float4(0.f, 0.f, 0.f, 0.f);
      float cslr = 0.f;
      for (int cb = 0; cb < c; cb += MAXC) {
        int nv = min(MAXC, c - cb);
        for (int n = nL; n < nv; n += 128) {
          const uint4* rowp = aggb4 + (size_t)(st + cb + n) * 16;
          float pr = 0.f;
#pragma unroll 4
          for (int k = 0; k < 16; k++) {
            uint4 u = rowp[k];
            float4 wa = *(const float4*)&wv_sh[tL][k * 8];
            float4 wb = *(const float4*)&wv_sh[tL][k * 8 + 4];
            pr += bf_lo(u.x) * wa.x + bf_hi(u.x) * wa.y + bf_lo(u.y) * wa.z +
                  bf_hi(u.y) * wa.w;
            pr += bf_lo(u.z) * wb.x + bf_hi(u.z) * wb.y + bf_lo(u.w) * wb.z +
                  bf_hi(u.w) * wb.w;
          }
          dt_sh[n][tL] = pr + bv_sh[tL];
        }
        __syncthreads();
        if (tid < nv) {
          float l0 = dt_sh[tid][0], l1 = dt_sh[tid][1], l2 = dt_sh[tid][2],
                l3 = dt_sh[tid][3], l4 = dt_sh[tid][4], l5 = dt_sh[tid][5],
                l6 = dt_sh[tid][6], l7 = dt_sh[tid][7];
          float m = fmaxf(fmaxf(fmaxf(l0, l1), fmaxf(l2, l3)),
                          fmaxf(fmaxf(l4, l5), fmaxf(l6, l7)));
          float e0 = __expf(l0 - m), e1 = __expf(l1 - m), e2 = __expf(l2 - m),
                e3 = __expf(l3 - m), e4 = __expf(l4 - m), e5 = __expf(l5 - m),
                e6 = __expf(l6 - m), e7 = __expf(l7 - m);
          float iz = 1.0f / (e0 + e1 + e2 + e3 + e4 + e5 + e6 + e7);
          dt_sh[tid][0] = e0 * iz;
          dt_sh[tid][1] = e1 * iz;
          dt_sh[tid][2] = e2 * iz;
          dt_sh[tid][3] = e3 * iz;
          dt_sh[tid][4] = e4 * iz;
          dt_sh[tid][5] = e5 * iz;
          dt_sh[tid][6] = e6 * iz;
          dt_sh[tid][7] = e7 * iz;
        }
        __syncthreads();
        for (int nj = rep; nj < nv; nj += 4) {
          float cj = dt_sh[nj][tA];
          uint2 u = aggb2[(size_t)(st + cb + nj) * 32 + l32];
          acc.x += cj * bf_lo(u.x);
          acc.y += cj * bf_hi(u.x);
          acc.z += cj * bf_lo(u.y);
          acc.w += cj * bf_hi(u.y);
          if (l32 == 0) cslr += cj;
        }
        __syncthreads();
      }
      int d4 = l32 << 2;
      if (rep > 0) *(float4*)&scratch[(((rep - 1) << 3) + tA) * 128 + d4] = acc;
      if (l32 == 0) csp_sh[tid >> 5] = cslr;
      __syncthreads();
      if (rep == 0) {
#pragma unroll
        for (int m = 0; m < 3; m++) {
          float4 o4 = *(const float4*)&scratch[((m << 3) + tA) * 128 + d4];
          acc.x += o4.x;
          acc.y += o4.y;
          acc.z += o4.z;
          acc.w += o4.w;
        }
        *(float4*)&ac_sh[tA][d4] = acc;
      }
      if (tid < T_CAPS)
        csum_sh[tid] = csp_sh[tid * 4] + csp_sh[tid * 4 + 1] + csp_sh[tid * 4 + 2] +
                       csp_sh[tid * 4 + 3];
      __syncthreads();
    }
  }
}

extern "C" void kernel_launch(void* const* d_in, const int* in_sizes, int n_in, void* d_out,
                              int out_size, void* d_ws, size_t ws_size, hipStream_t stream) {
  const float* x = (const float*)d_in[0];
  const float* ew = (const float*)d_in[1];
  const float* gamma = (const float*)d_in[2];
  const float* beta = (const float*)d_in[3];
  const float* W = (const float*)d_in[4];
  const float* bias = (const float*)d_in[5];
  const int* eidx = (const int*)d_in[6];
  const int* batch = (const int*)d_in[7];
  float* out = (float*)d_out;
  float* w = (float*)d_ws;

  const int* row = eidx;
  const int* col = eidx + N_EDGES;

  int* cnt_in = (int*)w;                       // N
  int* cursor = cnt_in + N_NODES;              // N
  int* start = cursor + N_NODES;               // 258
  int* node_start = start + 258;               // N
  int* bsum = node_start + N_NODES;            // 256
  int* bar = bsum + 256;                       // 16
  float* scale = (float*)(bar + 16);           // 128
  float* shift = scale + 128;                  // 128
  float* dis = shift + 128;                    // N
  float* rawxsum = dis + N_NODES;              // 256*128
  float* rawxsq = rawxsum + N_GRAPHS * D_DIM;  // 256*128
  float* WT = rawxsq + N_GRAPHS * D_DIM;       // 131072
  int2* csr = (int2*)(WT + T_CAPS * D_DIM * D_DIM);          // E
  __hip_bfloat162* y = (__hip_bfloat162*)(csr + N_EDGES);    // N*64
  unsigned* agg_bf = (unsigned*)(y + (size_t)N_NODES * 64);  // N*64

  hipMemsetAsync(bar, 0, 16 * sizeof(int), stream);
  mega<<<N_GRAPHS, NTHR, 0, stream>>>(x, ew, gamma, beta, W, bias, row, col, batch, cnt_in,
                                      cursor, start, node_start, bsum, scale, shift, dis,
                                      rawxsum, rawxsq, WT, csr, y, agg_bf, out, bar);
}

// Round 9
// 316.038 us; speedup vs baseline: 1.7112x; 1.7112x over previous
//
#include <hip/hip_runtime.h>
#include <hip/hip_bf16.h>
#include <math.h>

#define N_NODES 51200
#define N_EDGES 614400
#define N_GRAPHS 256
#define T_CAPS 8
#define D_DIM 128
#define BN_EPS 1e-5f
#define MAXC 512  // max nodes per graph per chunk (mean 200, sd ~14)

__device__ inline float waveReduceSum(float v) {
#pragma unroll
  for (int off = 1; off < 64; off <<= 1) v += __shfl_xor(v, off, 64);
  return v;
}
__device__ inline float bf_lo(unsigned u) { return __uint_as_float(u << 16); }
__device__ inline float bf_hi(unsigned u) { return __uint_as_float(u & 0xffff0000u); }

// ---- L1: zero counters + graph bounds (sorted batch) + W transpose ----
__global__ void __launch_bounds__(256) prep(const int* __restrict__ batch,
                                            const float* __restrict__ W,
                                            int* __restrict__ start, int* __restrict__ cnt_in,
                                            int* __restrict__ cursor, float* __restrict__ deg,
                                            float* __restrict__ WT) {
  int i = blockIdx.x * 256 + threadIdx.x;  // 51200 threads
  cnt_in[i] = 0;
  cursor[i] = 0;
  deg[i] = 0.f;
  int bn = batch[i];
  if (i == 0) {
    for (int g = 0; g <= bn; g++) start[g] = 0;
  } else {
    int bp = batch[i - 1];
    for (int g = bp + 1; g <= bn; g++) start[g] = i;
  }
  if (i == N_NODES - 1)
    for (int g = bn + 1; g <= N_GRAPHS; g++) start[g] = N_NODES;
  // coalesced read of W, scattered write into WT (L2 absorbs; 512 KB)
  for (int j = i; j < T_CAPS * D_DIM * D_DIM; j += N_NODES) {
    int t = j >> 14, r = j & 16383;
    int o = r >> 7, oo = r & 127;
    WT[(t << 14) + (oo << 7) + o] = W[j];
  }
}

// ---- L2: edge histogram+weighted degree (blocks 0..2399) || xstats (2400..2655) ----
__global__ void __launch_bounds__(256) hist_x(const int* __restrict__ col,
                                              const float* __restrict__ ew,
                                              const float* __restrict__ x,
                                              const int* __restrict__ start,
                                              int* __restrict__ cnt_in, float* __restrict__ deg,
                                              float* __restrict__ rawxsum,
                                              float* __restrict__ rawxsq) {
  int bid = blockIdx.x, tid = threadIdx.x;
  if (bid < 2400) {  // 2400*256 = 614400 edges
    int e = bid * 256 + tid;
    int c = col[e];
    atomicAdd(&cnt_in[c], 1);
    atomicAdd(&deg[c], ew[e]);
    return;
  }
  int g = bid - 2400;
  int d = tid & 127, h = tid >> 7;
  int st = start[g], en = start[g + 1];
  float s = 0.f, s2 = 0.f;
  for (int n = st + h; n < en; n += 2) {
    float v = x[n * D_DIM + d];
    s += v;
    s2 += v * v;
  }
  __shared__ float ls[256], ls2[256];
  ls[tid] = s;
  ls2[tid] = s2;
  __syncthreads();
  if (h == 0) {
    rawxsum[g * D_DIM + d] = ls[d] + ls[d + 128];
    rawxsq[g * D_DIM + d] = ls2[d] + ls2[d + 128];
  }
}

// ---- L3: chunk sums of cnt_in (blocks 0..199) || BN finalize (200..327) ----
__global__ void __launch_bounds__(256) scan_bn(const int* __restrict__ cnt_in,
                                               int* __restrict__ bsum,
                                               const float* __restrict__ rawxsum,
                                               const float* __restrict__ rawxsq,
                                               const float* __restrict__ gamma,
                                               const float* __restrict__ beta,
                                               float* __restrict__ scale,
                                               float* __restrict__ shift) {
  int bid = blockIdx.x, tid = threadIdx.x;
  if (bid < 200) {
    __shared__ int li[256];
    li[tid] = cnt_in[bid * 256 + tid];
    __syncthreads();
    for (int off = 128; off; off >>= 1) {
      if (tid < off) li[tid] += li[tid + off];
      __syncthreads();
    }
    if (tid == 0) bsum[bid] = li[0];
    return;
  }
  int d = bid - 200;  // 128 blocks, one per feature
  __shared__ float ls[256], ls2[256];
  ls[tid] = rawxsum[tid * D_DIM + d];
  ls2[tid] = rawxsq[tid * D_DIM + d];
  __syncthreads();
  for (int off = 128; off; off >>= 1) {
    if (tid < off) {
      ls[tid] += ls[tid + off];
      ls2[tid] += ls2[tid + off];
    }
    __syncthreads();
  }
  if (tid == 0) {
    float mu = ls[0] * (1.0f / N_NODES);
    float var = ls2[0] * (1.0f / N_NODES) - mu * mu;
    float rstd = rsqrtf(var + BN_EPS);
    float sc = gamma[d] * rstd;
    scale[d] = sc;
    shift[d] = beta[d] - mu * sc;
  }
}

// ---- L4: node_start = exclusive scan (each block re-reduces its bsum prefix) ----
__global__ void __launch_bounds__(256) scan_fin2(const int* __restrict__ cnt_in,
                                                 const int* __restrict__ bsum,
                                                 int* __restrict__ node_start) {
  __shared__ int ls[256];
  int t = threadIdx.x, bid = blockIdx.x;
  ls[t] = (t < bid) ? bsum[t] : 0;
  __syncthreads();
  for (int off = 128; off; off >>= 1) {
    if (t < off) ls[t] += ls[t + off];
    __syncthreads();
  }
  int base = ls[0];
  __syncthreads();
  int idx = bid * 256 + t;
  int v = cnt_in[idx];
  ls[t] = v;
  __syncthreads();
  for (int off = 1; off < 256; off <<= 1) {
    int u = (t >= off) ? ls[t - off] : 0;
    __syncthreads();
    ls[t] += u;
    __syncthreads();
  }
  node_start[idx] = base + ls[t] - v;
}

// ---- L5: fill_csr (blocks 0..2399) || make_y elementwise (2400..15199) ----
__global__ void __launch_bounds__(256) csr_y(const int* __restrict__ row,
                                             const int* __restrict__ col,
                                             const float* __restrict__ ew,
                                             const int* __restrict__ node_start,
                                             int* __restrict__ cursor, int2* __restrict__ csr,
                                             const float* __restrict__ x,
                                             const float* __restrict__ scale,
                                             const float* __restrict__ shift,
                                             const float* __restrict__ deg,
                                             float* __restrict__ dis,
                                             __hip_bfloat162* __restrict__ y) {
  int bid = blockIdx.x, tid = threadIdx.x;
  if (bid < 2400) {
    int e = bid * 256 + tid;
    int c = col[e];
    int slot = node_start[c] + atomicAdd(&cursor[c], 1);
    csr[slot] = make_int2(row[e], __float_as_int(ew[e]));
    return;
  }
  int idx = (bid - 2400) * 256 + tid;  // 3,276,800 = N*64
  int n = idx >> 6, l = idx & 63;
  float dv = deg[n] + 1.0f;  // + self-loop weight
  float dn = dv > 0.f ? rsqrtf(fmaxf(dv, 1e-12f)) : 0.f;
  if (l == 0) dis[n] = dn;
  float2 scv = ((const float2*)scale)[l];
  float2 shv = ((const float2*)shift)[l];
  float2 xv = ((const float2*)x)[n * 64 + l];
  float2 yv;
  yv.x = dn * (xv.x * scv.x + shv.x);
  yv.y = dn * (xv.y * scv.y + shv.y);
  y[n * 64 + l] = __float22bfloat162_rn(yv);
}

// ---- L6: one wave per node: agg[n] = bf16( dis[n]*(y[n] + sum_e ew_e*y[src_e]) ) ----
__global__ void __launch_bounds__(256) node_gather(const __hip_bfloat162* __restrict__ y,
                                                   const float* __restrict__ dis,
                                                   const int* __restrict__ node_start,
                                                   const int* __restrict__ cnt_in,
                                                   const int2* __restrict__ csr,
                                                   __hip_bfloat162* __restrict__ agg) {
  int n = blockIdx.x * 4 + (threadIdx.x >> 6);
  int lane = threadIdx.x & 63;
  int st = node_start[n], c = cnt_in[n];
  float2 a = __bfloat1622float2(y[n * 64 + lane]);  // self term
  int j = 0;
  for (; j + 4 <= c; j += 4) {
    int2 e0 = csr[st + j], e1 = csr[st + j + 1], e2 = csr[st + j + 2], e3 = csr[st + j + 3];
    float2 v0 = __bfloat1622float2(y[e0.x * 64 + lane]);
    float2 v1 = __bfloat1622float2(y[e1.x * 64 + lane]);
    float2 v2 = __bfloat1622float2(y[e2.x * 64 + lane]);
    float2 v3 = __bfloat1622float2(y[e3.x * 64 + lane]);
    float w0 = __int_as_float(e0.y), w1 = __int_as_float(e1.y);
    float w2 = __int_as_float(e2.y), w3 = __int_as_float(e3.y);
    a.x += w0 * v0.x + w1 * v1.x + w2 * v2.x + w3 * v3.x;
    a.y += w0 * v0.y + w1 * v1.y + w2 * v2.y + w3 * v3.y;
  }
  for (; j < c; j++) {
    int2 e = csr[st + j];
    float2 v = __bfloat1622float2(y[e.x * 64 + lane]);
    float w = __int_as_float(e.y);
    a.x += w * v.x;
    a.y += w * v.y;
  }
  float dn = dis[n];
  a.x *= dn;
  a.y *= dn;
  agg[n * 64 + lane] = __float22bfloat162_rn(a);
}

// ---- L7: routing v3 (R7-proven): telescoped wv/bv, global agg reads, LDS softmax ----
__global__ void __launch_bounds__(1024) routing_fused(
    const unsigned* __restrict__ agg_bf, const int* __restrict__ start,
    const float* __restrict__ W, const float* __restrict__ WT, const float* __restrict__ bias,
    const float* __restrict__ rawxsum, const float* __restrict__ scale,
    const float* __restrict__ shift, float* __restrict__ out) {
  int g = blockIdx.x;
  int tid = threadIdx.x;
  int st = start[g], c = start[g + 1] - st;

  __shared__ float dt_sh[MAXC][T_CAPS];
  __shared__ float ac_sh[T_CAPS][D_DIM];
  __shared__ float s_sh[T_CAPS][D_DIM];
  __shared__ float wv_sh[T_CAPS][132];
  __shared__ float csum_sh[T_CAPS], bv_sh[T_CAPS], f_sh[T_CAPS], s2p[T_CAPS][2];
  __shared__ float csp_sh[32];

  float* scratch = &dt_sh[0][0];
  const uint2* aggb2 = (const uint2*)agg_bf;
  const uint4* aggb4 = (const uint4*)agg_bf;

  for (int i = tid; i < T_CAPS * 132; i += 1024) (&wv_sh[0][0])[i] = 0.f;
  if (tid < T_CAPS) {
    bv_sh[tid] = 0.f;
    csum_sh[tid] = 0.125f * (float)c;
  }
  {
    int d2 = tid & 63, h = tid >> 6;
    float sx = 0.f, sy = 0.f;
    for (int n = st + h; n < st + c; n += 16) {
      unsigned u = agg_bf[n * 64 + d2];
      sx += bf_lo(u);
      sy += bf_hi(u);
    }
    scratch[h * 128 + d2 * 2] = sx;
    scratch[h * 128 + d2 * 2 + 1] = sy;
  }
  __syncthreads();
  if (tid < 128) {
    float s = 0.f;
#pragma unroll
    for (int h = 0; h < 16; h++) s += scratch[h * 128 + tid];
    s *= 0.125f;
#pragma unroll
    for (int t = 0; t < T_CAPS; t++) ac_sh[t][tid] = s;
  }
  __syncthreads();

  int tG = tid >> 7, oG = tid & 127;
  int nL = tid >> 3, tL = tid & 7;
  int tA = tid >> 7, rep = (tid >> 5) & 3, l32 = tid & 31;

  for (int iter = 0; iter < 3; iter++) {
    {  // GEMV1
      const float* Wt = W + (tG << 14);
      float s = 0.f;
#pragma unroll 8
      for (int dd = 0; dd < D_DIM; dd++) s += ac_sh[tG][dd] * Wt[dd * D_DIM + oG];
      s += csum_sh[tG] * bias[tG * D_DIM + oG];
      if (iter == 2) {
        float cf = (float)c;
        float ic = 1.0f / fmaxf(cf, 1.0f);
        s += (scale[oG] * rawxsum[g * D_DIM + oG] + cf * shift[oG]) * ic;
      }
      s_sh[tG][oG] = s;
      float p = waveReduceSum(s * s);
      if ((tid & 63) == 0) s2p[tG][(tid >> 6) & 1] = p;
    }
    __syncthreads();
    if (tid < T_CAPS) {
      float s2 = s2p[tid][0] + s2p[tid][1];
      float f = (s2 / (1.0f + s2)) * rsqrtf(s2 + 1e-16f);
      f_sh[tid] = f;
      if (iter == 2) out[g * T_CAPS + tid] = sqrtf(f * f * s2 + 1e-16f);
    }
    __syncthreads();
    if (iter == 2) return;
    s_sh[tG][oG] *= f_sh[tG];
    __syncthreads();
    {  // GEMV2 (running wv/bv)
      const float* WTt = WT + (tG << 14);
      float s = 0.f;
#pragma unroll 8
      for (int oo = 0; oo < D_DIM; oo++) s += s_sh[tG][oo] * WTt[oo * D_DIM + oG];
      wv_sh[tG][oG] += s;
      float bp = bias[tG * D_DIM + oG] * s_sh[tG][oG];
      bp = waveReduceSum(bp);
      if ((tid & 63) == 0) s2p[tG][(tid >> 6) & 1] = bp;
    }
    __syncthreads();
    if (tid < T_CAPS) bv_sh[tid] += s2p[tid][0] + s2p[tid][1];
    __syncthreads();

    float4 acc = make_float4(0.f, 0.f, 0.f, 0.f);
    float cslr = 0.f;
    for (int cb = 0; cb < c; cb += MAXC) {
      int nv = min(MAXC, c - cb);
      for (int n = nL; n < nv; n += 128) {
        const uint4* rowp = aggb4 + (size_t)(st + cb + n) * 16;
        float pr = 0.f;
#pragma unroll 4
        for (int k = 0; k < 16; k++) {
          uint4 u = rowp[k];
          float4 wa = *(const float4*)&wv_sh[tL][k * 8];
          float4 wb = *(const float4*)&wv_sh[tL][k * 8 + 4];
          pr += bf_lo(u.x) * wa.x + bf_hi(u.x) * wa.y + bf_lo(u.y) * wa.z + bf_hi(u.y) * wa.w;
          pr += bf_lo(u.z) * wb.x + bf_hi(u.z) * wb.y + bf_lo(u.w) * wb.z + bf_hi(u.w) * wb.w;
        }
        dt_sh[n][tL] = pr + bv_sh[tL];
      }
      __syncthreads();
      if (tid < nv) {
        float l0 = dt_sh[tid][0], l1 = dt_sh[tid][1], l2 = dt_sh[tid][2], l3 = dt_sh[tid][3];
        float l4 = dt_sh[tid][4], l5 = dt_sh[tid][5], l6 = dt_sh[tid][6], l7 = dt_sh[tid][7];
        float m = fmaxf(fmaxf(fmaxf(l0, l1), fmaxf(l2, l3)),
                        fmaxf(fmaxf(l4, l5), fmaxf(l6, l7)));
        float e0 = __expf(l0 - m), e1 = __expf(l1 - m), e2 = __expf(l2 - m),
              e3 = __expf(l3 - m), e4 = __expf(l4 - m), e5 = __expf(l5 - m),
              e6 = __expf(l6 - m), e7 = __expf(l7 - m);
        float iz = 1.0f / (e0 + e1 + e2 + e3 + e4 + e5 + e6 + e7);
        dt_sh[tid][0] = e0 * iz;
        dt_sh[tid][1] = e1 * iz;
        dt_sh[tid][2] = e2 * iz;
        dt_sh[tid][3] = e3 * iz;
        dt_sh[tid][4] = e4 * iz;
        dt_sh[tid][5] = e5 * iz;
        dt_sh[tid][6] = e6 * iz;
        dt_sh[tid][7] = e7 * iz;
      }
      __syncthreads();
      for (int nj = rep; nj < nv; nj += 4) {
        float cj = dt_sh[nj][tA];
        uint2 u = aggb2[(size_t)(st + cb + nj) * 32 + l32];
        acc.x += cj * bf_lo(u.x);
        acc.y += cj * bf_hi(u.x);
        acc.z += cj * bf_lo(u.y);
        acc.w += cj * bf_hi(u.y);
        if (l32 == 0) cslr += cj;
      }
      __syncthreads();
    }
    int d4 = l32 << 2;
    if (rep > 0) *(float4*)&scratch[(((rep - 1) << 3) + tA) * 128 + d4] = acc;
    if (l32 == 0) csp_sh[tid >> 5] = cslr;
    __syncthreads();
    if (rep == 0) {
#pragma unroll
      for (int m = 0; m < 3; m++) {
        float4 o4 = *(const float4*)&scratch[((m << 3) + tA) * 128 + d4];
        acc.x += o4.x;
        acc.y += o4.y;
        acc.z += o4.z;
        acc.w += o4.w;
      }
      *(float4*)&ac_sh[tA][d4] = acc;
    }
    if (tid < T_CAPS)
      csum_sh[tid] = csp_sh[tid * 4] + csp_sh[tid * 4 + 1] + csp_sh[tid * 4 + 2] +
                     csp_sh[tid * 4 + 3];
    __syncthreads();
  }
}

extern "C" void kernel_launch(void* const* d_in, const int* in_sizes, int n_in, void* d_out,
                              int out_size, void* d_ws, size_t ws_size, hipStream_t stream) {
  const float* x = (const float*)d_in[0];
  const float* ew = (const float*)d_in[1];
  const float* gamma = (const float*)d_in[2];
  const float* beta = (const float*)d_in[3];
  const float* W = (const float*)d_in[4];
  const float* bias = (const float*)d_in[5];
  const int* eidx = (const int*)d_in[6];
  const int* batch = (const int*)d_in[7];
  float* out = (float*)d_out;
  float* w = (float*)d_ws;

  const int* row = eidx;
  const int* col = eidx + N_EDGES;

  int* cnt_in = (int*)w;                       // N (zeroed in prep)
  int* cursor = cnt_in + N_NODES;              // N (zeroed in prep)
  float* deg = (float*)(cursor + N_NODES);     // N (zeroed in prep)
  int* start = (int*)(deg + N_NODES);          // 258
  int* node_start = start + 258;               // N
  int* bsum = node_start + N_NODES;            // 256
  float* scale = (float*)(bsum + 256);         // 128
  float* shift = scale + 128;                  // 128
  float* dis = shift + 128;                    // N
  float* rawxsum = dis + N_NODES;              // 256*128
  float* rawxsq = rawxsum + N_GRAPHS * D_DIM;  // 256*128
  float* WT = rawxsq + N_GRAPHS * D_DIM;       // 131072
  int2* csr = (int2*)(WT + T_CAPS * D_DIM * D_DIM);          // E
  __hip_bfloat162* y = (__hip_bfloat162*)(csr + N_EDGES);    // N*64
  unsigned* agg_bf = (unsigned*)(y + (size_t)N_NODES * 64);  // N*64

  prep<<<N_NODES / 256, 256, 0, stream>>>(batch, W, start, cnt_in, cursor, deg, WT);
  hist_x<<<2400 + N_GRAPHS, 256, 0, stream>>>(col, ew, x, start, cnt_in, deg, rawxsum, rawxsq);
  scan_bn<<<200 + D_DIM, 256, 0, stream>>>(cnt_in, bsum, rawxsum, rawxsq, gamma, beta, scale,
                                           shift);
  scan_fin2<<<200, 256, 0, stream>>>(cnt_in, bsum, node_start);
  csr_y<<<2400 + 12800, 256, 0, stream>>>(row, col, ew, node_start, cursor, csr, x, scale,
                                          shift, deg, dis, y);
  node_gather<<<N_NODES / 4, 256, 0, stream>>>(y, dis, node_start, cnt_in, csr,
                                               (__hip_bfloat162*)agg_bf);
  routing_fused<<<N_GRAPHS, 1024, 0, stream>>>(agg_bf, start, W, WT, bias, rawxsum, scale,
                                               shift, out);
}

// Round 10
// 264.206 us; speedup vs baseline: 2.0469x; 1.1962x over previous
//
#include <hip/hip_runtime.h>
#include <hip/hip_bf16.h>
#include <math.h>

#define N_NODES 51200
#define N_EDGES 614400
#define N_GRAPHS 256
#define T_CAPS 8
#define D_DIM 128
#define BN_EPS 1e-5f
#define MAXC 512  // routing chunk size (graph size mean 200, sd ~14)
#define BINCAP 48 // csr slots per node (in-degree mean 12, sd 3.5, exp-max ~28)

__device__ inline float waveReduceSum(float v) {
#pragma unroll
  for (int off = 1; off < 64; off <<= 1) v += __shfl_xor(v, off, 64);
  return v;
}
__device__ inline float bf_lo(unsigned u) { return __uint_as_float(u << 16); }
__device__ inline float bf_hi(unsigned u) { return __uint_as_float(u & 0xffff0000u); }

// ---- L1: zero cursor + graph bounds (sorted batch) + W transpose ----
__global__ void __launch_bounds__(256) prep(const int* __restrict__ batch,
                                            const float* __restrict__ W,
                                            int* __restrict__ start, int* __restrict__ cursor,
                                            float* __restrict__ WT) {
  int i = blockIdx.x * 256 + threadIdx.x;  // 51200 threads
  cursor[i] = 0;
  int bn = batch[i];
  if (i == 0) {
    for (int g = 0; g <= bn; g++) start[g] = 0;
  } else {
    int bp = batch[i - 1];
    for (int g = bp + 1; g <= bn; g++) start[g] = i;
  }
  if (i == N_NODES - 1)
    for (int g = bn + 1; g <= N_GRAPHS; g++) start[g] = N_NODES;
  // coalesced read of W, scattered write into WT (512 KB, L2 absorbs)
  for (int j = i; j < T_CAPS * D_DIM * D_DIM; j += N_NODES) {
    int t = j >> 14, r = j & 16383;
    int o = r >> 7, oo = r & 127;
    WT[(t << 14) + (oo << 7) + o] = W[j];
  }
}

// ---- L2: binned-CSR fill (blocks 0..2399) || per-graph xstats (2400..2655) ----
// Single atomic per edge: the slot allocator doubles as the in-degree count.
__global__ void __launch_bounds__(256) fill_x(const int* __restrict__ row,
                                              const int* __restrict__ col,
                                              const float* __restrict__ ew,
                                              int* __restrict__ cursor, int2* __restrict__ csr,
                                              const float* __restrict__ x,
                                              const int* __restrict__ start,
                                              float* __restrict__ rawxsum,
                                              float* __restrict__ rawxsq) {
  int bid = blockIdx.x, tid = threadIdx.x;
  if (bid < 2400) {  // 2400*256 = 614400 edges
    int e = bid * 256 + tid;
    int c = col[e];
    int slot = atomicAdd(&cursor[c], 1);
    if (slot < BINCAP) csr[c * BINCAP + slot] = make_int2(row[e], __float_as_int(ew[e]));
    return;
  }
  int g = bid - 2400;
  int d = tid & 127, h = tid >> 7;
  int st = start[g], en = start[g + 1];
  float s = 0.f, s2 = 0.f;
  for (int n = st + h; n < en; n += 2) {
    float v = x[n * D_DIM + d];
    s += v;
    s2 += v * v;
  }
  __shared__ float ls[256], ls2[256];
  ls[tid] = s;
  ls2[tid] = s2;
  __syncthreads();
  if (h == 0) {
    rawxsum[g * D_DIM + d] = ls[d] + ls[d + 128];
    rawxsq[g * D_DIM + d] = ls2[d] + ls2[d + 128];
  }
}

// ---- L3: BN finalize: one block per feature d ----
__global__ void __launch_bounds__(256) bn_fin(const float* __restrict__ rawxsum,
                                              const float* __restrict__ rawxsq,
                                              const float* __restrict__ gamma,
                                              const float* __restrict__ beta,
                                              float* __restrict__ scale,
                                              float* __restrict__ shift) {
  int d = blockIdx.x;
  int tid = threadIdx.x;
  __shared__ float ls[256], ls2[256];
  ls[tid] = rawxsum[tid * D_DIM + d];
  ls2[tid] = rawxsq[tid * D_DIM + d];
  __syncthreads();
  for (int off = 128; off; off >>= 1) {
    if (tid < off) {
      ls[tid] += ls[tid + off];
      ls2[tid] += ls2[tid + off];
    }
    __syncthreads();
  }
  if (tid == 0) {
    float mu = ls[0] * (1.0f / N_NODES);
    float var = ls2[0] * (1.0f / N_NODES) - mu * mu;
    float rstd = rsqrtf(var + BN_EPS);
    float sc = gamma[d] * rstd;
    scale[d] = sc;
    shift[d] = beta[d] - mu * sc;
  }
}

// ---- L4: wave per node: deg from own csr bin, dis = rsqrt(deg+1), y = bf16(dis*xhat) ----
__global__ void __launch_bounds__(256) make_y(const float* __restrict__ x,
                                              const float* __restrict__ scale,
                                              const float* __restrict__ shift,
                                              const int* __restrict__ cursor,
                                              const int2* __restrict__ csr,
                                              float* __restrict__ dis,
                                              __hip_bfloat162* __restrict__ y) {
  int n = blockIdx.x * 4 + (threadIdx.x >> 6);
  int lane = threadIdx.x & 63;
  int c = min(cursor[n], BINCAP);
  float s = (lane < c) ? __int_as_float(csr[n * BINCAP + lane].y) : 0.f;
  s = waveReduceSum(s);
  float dv = s + 1.0f;  // + self-loop weight
  float dn = dv > 0.f ? rsqrtf(fmaxf(dv, 1e-12f)) : 0.f;
  if (lane == 0) dis[n] = dn;
  float2 scv = ((const float2*)scale)[lane];
  float2 shv = ((const float2*)shift)[lane];
  float2 xv = ((const float2*)x)[n * 64 + lane];
  float2 yv;
  yv.x = dn * (xv.x * scv.x + shv.x);
  yv.y = dn * (xv.y * scv.y + shv.y);
  y[n * 64 + lane] = __float22bfloat162_rn(yv);
}

// ---- L5: wave per node: agg[n] = bf16( dis[n]*(y[n] + sum_e ew_e*y[src_e]) ) ----
__global__ void __launch_bounds__(256) node_gather(const __hip_bfloat162* __restrict__ y,
                                                   const float* __restrict__ dis,
                                                   const int* __restrict__ cursor,
                                                   const int2* __restrict__ csr,
                                                   __hip_bfloat162* __restrict__ agg) {
  int n = blockIdx.x * 4 + (threadIdx.x >> 6);
  int lane = threadIdx.x & 63;
  int st = n * BINCAP, c = min(cursor[n], BINCAP);
  float2 a = __bfloat1622float2(y[n * 64 + lane]);  // self term
  int j = 0;
  for (; j + 4 <= c; j += 4) {
    int2 e0 = csr[st + j], e1 = csr[st + j + 1], e2 = csr[st + j + 2], e3 = csr[st + j + 3];
    float2 v0 = __bfloat1622float2(y[e0.x * 64 + lane]);
    float2 v1 = __bfloat1622float2(y[e1.x * 64 + lane]);
    float2 v2 = __bfloat1622float2(y[e2.x * 64 + lane]);
    float2 v3 = __bfloat1622float2(y[e3.x * 64 + lane]);
    float w0 = __int_as_float(e0.y), w1 = __int_as_float(e1.y);
    float w2 = __int_as_float(e2.y), w3 = __int_as_float(e3.y);
    a.x += w0 * v0.x + w1 * v1.x + w2 * v2.x + w3 * v3.x;
    a.y += w0 * v0.y + w1 * v1.y + w2 * v2.y + w3 * v3.y;
  }
  for (; j < c; j++) {
    int2 e = csr[st + j];
    float2 v = __bfloat1622float2(y[e.x * 64 + lane]);
    float w = __int_as_float(e.y);
    a.x += w * v.x;
    a.y += w * v.y;
  }
  float dn = dis[n];
  a.x *= dn;
  a.y *= dn;
  agg[n * 64 + lane] = __float22bfloat162_rn(a);
}

// ---- L6: routing v3 (R7-proven): telescoped wv/bv, global agg reads, LDS softmax ----
__global__ void __launch_bounds__(1024) routing_fused(
    const unsigned* __restrict__ agg_bf, const int* __restrict__ start,
    const float* __restrict__ W, const float* __restrict__ WT, const float* __restrict__ bias,
    const float* __restrict__ rawxsum, const float* __restrict__ scale,
    const float* __restrict__ shift, float* __restrict__ out) {
  int g = blockIdx.x;
  int tid = threadIdx.x;
  int st = start[g], c = start[g + 1] - st;

  __shared__ float dt_sh[MAXC][T_CAPS];
  __shared__ float ac_sh[T_CAPS][D_DIM];
  __shared__ float s_sh[T_CAPS][D_DIM];
  __shared__ float wv_sh[T_CAPS][132];
  __shared__ float csum_sh[T_CAPS], bv_sh[T_CAPS], f_sh[T_CAPS], s2p[T_CAPS][2];
  __shared__ float csp_sh[32];

  float* scratch = &dt_sh[0][0];
  const uint2* aggb2 = (const uint2*)agg_bf;
  const uint4* aggb4 = (const uint4*)agg_bf;

  for (int i = tid; i < T_CAPS * 132; i += 1024) (&wv_sh[0][0])[i] = 0.f;
  if (tid < T_CAPS) {
    bv_sh[tid] = 0.f;
    csum_sh[tid] = 0.125f * (float)c;
  }
  {
    int d2 = tid & 63, h = tid >> 6;
    float sx = 0.f, sy = 0.f;
    for (int n = st + h; n < st + c; n += 16) {
      unsigned u = agg_bf[n * 64 + d2];
      sx += bf_lo(u);
      sy += bf_hi(u);
    }
    scratch[h * 128 + d2 * 2] = sx;
    scratch[h * 128 + d2 * 2 + 1] = sy;
  }
  __syncthreads();
  if (tid < 128) {
    float s = 0.f;
#pragma unroll
    for (int h = 0; h < 16; h++) s += scratch[h * 128 + tid];
    s *= 0.125f;
#pragma unroll
    for (int t = 0; t < T_CAPS; t++) ac_sh[t][tid] = s;
  }
  __syncthreads();

  int tG = tid >> 7, oG = tid & 127;
  int nL = tid >> 3, tL = tid & 7;
  int tA = tid >> 7, rep = (tid >> 5) & 3, l32 = tid & 31;

  for (int iter = 0; iter < 3; iter++) {
    {  // GEMV1
      const float* Wt = W + (tG << 14);
      float s = 0.f;
#pragma unroll 8
      for (int dd = 0; dd < D_DIM; dd++) s += ac_sh[tG][dd] * Wt[dd * D_DIM + oG];
      s += csum_sh[tG] * bias[tG * D_DIM + oG];
      if (iter == 2) {
        float cf = (float)c;
        float ic = 1.0f / fmaxf(cf, 1.0f);
        s += (scale[oG] * rawxsum[g * D_DIM + oG] + cf * shift[oG]) * ic;
      }
      s_sh[tG][oG] = s;
      float p = waveReduceSum(s * s);
      if ((tid & 63) == 0) s2p[tG][(tid >> 6) & 1] = p;
    }
    __syncthreads();
    if (tid < T_CAPS) {
      float s2 = s2p[tid][0] + s2p[tid][1];
      float f = (s2 / (1.0f + s2)) * rsqrtf(s2 + 1e-16f);
      f_sh[tid] = f;
      if (iter == 2) out[g * T_CAPS + tid] = sqrtf(f * f * s2 + 1e-16f);
    }
    __syncthreads();
    if (iter == 2) return;
    s_sh[tG][oG] *= f_sh[tG];
    __syncthreads();
    {  // GEMV2 (running wv/bv)
      const float* WTt = WT + (tG << 14);
      float s = 0.f;
#pragma unroll 8
      for (int oo = 0; oo < D_DIM; oo++) s += s_sh[tG][oo] * WTt[oo * D_DIM + oG];
      wv_sh[tG][oG] += s;
      float bp = bias[tG * D_DIM + oG] * s_sh[tG][oG];
      bp = waveReduceSum(bp);
      if ((tid & 63) == 0) s2p[tG][(tid >> 6) & 1] = bp;
    }
    __syncthreads();
    if (tid < T_CAPS) bv_sh[tid] += s2p[tid][0] + s2p[tid][1];
    __syncthreads();

    float4 acc = make_float4(0.f, 0.f, 0.f, 0.f);
    float cslr = 0.f;
    for (int cb = 0; cb < c; cb += MAXC) {
      int nv = min(MAXC, c - cb);
      for (int n = nL; n < nv; n += 128) {
        const uint4* rowp = aggb4 + (size_t)(st + cb + n) * 16;
        float pr = 0.f;
#pragma unroll 4
        for (int k = 0; k < 16; k++) {
          uint4 u = rowp[k];
          float4 wa = *(const float4*)&wv_sh[tL][k * 8];
          float4 wb = *(const float4*)&wv_sh[tL][k * 8 + 4];
          pr += bf_lo(u.x) * wa.x + bf_hi(u.x) * wa.y + bf_lo(u.y) * wa.z + bf_hi(u.y) * wa.w;
          pr += bf_lo(u.z) * wb.x + bf_hi(u.z) * wb.y + bf_lo(u.w) * wb.z + bf_hi(u.w) * wb.w;
        }
        dt_sh[n][tL] = pr + bv_sh[tL];
      }
      __syncthreads();
      if (tid < nv) {
        float l0 = dt_sh[tid][0], l1 = dt_sh[tid][1], l2 = dt_sh[tid][2], l3 = dt_sh[tid][3];
        float l4 = dt_sh[tid][4], l5 = dt_sh[tid][5], l6 = dt_sh[tid][6], l7 = dt_sh[tid][7];
        float m = fmaxf(fmaxf(fmaxf(l0, l1), fmaxf(l2, l3)),
                        fmaxf(fmaxf(l4, l5), fmaxf(l6, l7)));
        float e0 = __expf(l0 - m), e1 = __expf(l1 - m), e2 = __expf(l2 - m),
              e3 = __expf(l3 - m), e4 = __expf(l4 - m), e5 = __expf(l5 - m),
              e6 = __expf(l6 - m), e7 = __expf(l7 - m);
        float iz = 1.0f / (e0 + e1 + e2 + e3 + e4 + e5 + e6 + e7);
        dt_sh[tid][0] = e0 * iz;
        dt_sh[tid][1] = e1 * iz;
        dt_sh[tid][2] = e2 * iz;
        dt_sh[tid][3] = e3 * iz;
        dt_sh[tid][4] = e4 * iz;
        dt_sh[tid][5] = e5 * iz;
        dt_sh[tid][6] = e6 * iz;
        dt_sh[tid][7] = e7 * iz;
      }
      __syncthreads();
      for (int nj = rep; nj < nv; nj += 4) {
        float cj = dt_sh[nj][tA];
        uint2 u = aggb2[(size_t)(st + cb + nj) * 32 + l32];
        acc.x += cj * bf_lo(u.x);
        acc.y += cj * bf_hi(u.x);
        acc.z += cj * bf_lo(u.y);
        acc.w += cj * bf_hi(u.y);
        if (l32 == 0) cslr += cj;
      }
      __syncthreads();
    }
    int d4 = l32 << 2;
    if (rep > 0) *(float4*)&scratch[(((rep - 1) << 3) + tA) * 128 + d4] = acc;
    if (l32 == 0) csp_sh[tid >> 5] = cslr;
    __syncthreads();
    if (rep == 0) {
#pragma unroll
      for (int m = 0; m < 3; m++) {
        float4 o4 = *(const float4*)&scratch[((m << 3) + tA) * 128 + d4];
        acc.x += o4.x;
        acc.y += o4.y;
        acc.z += o4.z;
        acc.w += o4.w;
      }
      *(float4*)&ac_sh[tA][d4] = acc;
    }
    if (tid < T_CAPS)
      csum_sh[tid] = csp_sh[tid * 4] + csp_sh[tid * 4 + 1] + csp_sh[tid * 4 + 2] +
                     csp_sh[tid * 4 + 3];
    __syncthreads();
  }
}

extern "C" void kernel_launch(void* const* d_in, const int* in_sizes, int n_in, void* d_out,
                              int out_size, void* d_ws, size_t ws_size, hipStream_t stream) {
  const float* x = (const float*)d_in[0];
  const float* ew = (const float*)d_in[1];
  const float* gamma = (const float*)d_in[2];
  const float* beta = (const float*)d_in[3];
  const float* W = (const float*)d_in[4];
  const float* bias = (const float*)d_in[5];
  const int* eidx = (const int*)d_in[6];
  const int* batch = (const int*)d_in[7];
  float* out = (float*)d_out;
  float* w = (float*)d_ws;

  const int* row = eidx;
  const int* col = eidx + N_EDGES;

  int* cursor = (int*)w;                       // N (zeroed in prep; doubles as cnt)
  int* start = cursor + N_NODES;               // 258 (even pad)
  float* scale = (float*)(start + 258);        // 128
  float* shift = scale + 128;                  // 128
  float* dis = shift + 128;                    // N
  float* rawxsum = dis + N_NODES;              // 256*128
  float* rawxsq = rawxsum + N_GRAPHS * D_DIM;  // 256*128
  float* WT = rawxsq + N_GRAPHS * D_DIM;       // 131072
  int2* csr = (int2*)(WT + T_CAPS * D_DIM * D_DIM);          // N*BINCAP (19.7 MB)
  __hip_bfloat162* y = (__hip_bfloat162*)(csr + (size_t)N_NODES * BINCAP);  // N*64
  unsigned* agg_bf = (unsigned*)(y + (size_t)N_NODES * 64);  // N*64

  prep<<<N_NODES / 256, 256, 0, stream>>>(batch, W, start, cursor, WT);
  fill_x<<<2400 + N_GRAPHS, 256, 0, stream>>>(row, col, ew, cursor, csr, x, start, rawxsum,
                                              rawxsq);
  bn_fin<<<D_DIM, 256, 0, stream>>>(rawxsum, rawxsq, gamma, beta, scale, shift);
  make_y<<<N_NODES / 4, 256, 0, stream>>>(x, scale, shift, cursor, csr, dis, y);
  node_gather<<<N_NODES / 4, 256, 0, stream>>>(y, dis, cursor, csr, agg_bf ? (__hip_bfloat162*)agg_bf : nullptr);
  routing_fused<<<N_GRAPHS, 1024, 0, stream>>>(agg_bf, start, W, WT, bias, rawxsum, scale,
                                               shift, out);
}

// Round 11
// 255.661 us; speedup vs baseline: 2.1153x; 1.0334x over previous
//
#include <hip/hip_runtime.h>
#include <hip/hip_bf16.h>
#include <math.h>

#define N_NODES 51200
#define N_EDGES 614400
#define N_GRAPHS 256
#define T_CAPS 8
#define D_DIM 128
#define BN_EPS 1e-5f
#define MAXC 512   // routing chunk size (graph size mean 200, sd ~14)
#define BINCAP 48  // csr slots per node (in-degree mean 12, sd 3.5; max observed <= 48)
#define EPT 8      // edges per thread in fill_x

__device__ inline float waveReduceSum(float v) {
#pragma unroll
  for (int off = 1; off < 64; off <<= 1) v += __shfl_xor(v, off, 64);
  return v;
}
__device__ inline float bf_lo(unsigned u) { return __uint_as_float(u << 16); }
__device__ inline float bf_hi(unsigned u) { return __uint_as_float(u & 0xffff0000u); }

// ---- L1: zero cursor + graph bounds (sorted batch) + W transpose ----
__global__ void __launch_bounds__(256) prep(const int* __restrict__ batch,
                                            const float* __restrict__ W,
                                            int* __restrict__ start, int* __restrict__ cursor,
                                            float* __restrict__ WT) {
  int i = blockIdx.x * 256 + threadIdx.x;  // 51200 threads
  cursor[i] = 0;
  int bn = batch[i];
  if (i == 0) {
    for (int g = 0; g <= bn; g++) start[g] = 0;
  } else {
    int bp = batch[i - 1];
    for (int g = bp + 1; g <= bn; g++) start[g] = i;
  }
  if (i == N_NODES - 1)
    for (int g = bn + 1; g <= N_GRAPHS; g++) start[g] = N_NODES;
  // coalesced read of W, scattered write into WT (512 KB, L2 absorbs)
  for (int j = i; j < T_CAPS * D_DIM * D_DIM; j += N_NODES) {
    int t = j >> 14, r = j & 16383;
    int o = r >> 7, oo = r & 127;
    WT[(t << 14) + (oo << 7) + o] = W[j];
  }
}

// ---- L2: binned-CSR fill, 8 edges/thread (blocks 0..299) || xstats (300..555) ----
// Record = (row:16 | bf16(ew):16), 4 bytes. Single atomic per edge = slot alloc + count.
__global__ void __launch_bounds__(256) fill_x(const int* __restrict__ row,
                                              const int* __restrict__ col,
                                              const float* __restrict__ ew,
                                              int* __restrict__ cursor,
                                              unsigned* __restrict__ csr,
                                              const float* __restrict__ x,
                                              const int* __restrict__ start,
                                              float* __restrict__ rawxsum,
                                              float* __restrict__ rawxsq) {
  int bid = blockIdx.x, tid = threadIdx.x;
  if (bid < 300) {  // 300 blocks * 256 thr * 8 edges = 614400
    int e0 = bid * (256 * EPT) + tid;
    int cols[EPT];
    unsigned recs[EPT];
#pragma unroll
    for (int k = 0; k < EPT; k++) {
      int e = e0 + k * 256;
      cols[k] = col[e];
      unsigned u = __float_as_uint(ew[e]);
      unsigned wb = (u + 0x7FFFu + ((u >> 16) & 1u)) >> 16;  // RNE bf16 bits
      recs[k] = ((unsigned)row[e] << 16) | wb;
    }
#pragma unroll
    for (int k = 0; k < EPT; k++) {
      int slot = atomicAdd(&cursor[cols[k]], 1);
      if (slot < BINCAP) csr[cols[k] * BINCAP + slot] = recs[k];
    }
    return;
  }
  int g = bid - 300;
  int d = tid & 127, h = tid >> 7;
  int st = start[g], en = start[g + 1];
  float s = 0.f, s2 = 0.f;
  for (int n = st + h; n < en; n += 2) {
    float v = x[n * D_DIM + d];
    s += v;
    s2 += v * v;
  }
  __shared__ float ls[256], ls2[256];
  ls[tid] = s;
  ls2[tid] = s2;
  __syncthreads();
  if (h == 0) {
    rawxsum[g * D_DIM + d] = ls[d] + ls[d + 128];
    rawxsq[g * D_DIM + d] = ls2[d] + ls2[d + 128];
  }
}

// ---- L3: BN finalize: one block per feature d ----
__global__ void __launch_bounds__(256) bn_fin(const float* __restrict__ rawxsum,
                                              const float* __restrict__ rawxsq,
                                              const float* __restrict__ gamma,
                                              const float* __restrict__ beta,
                                              float* __restrict__ scale,
                                              float* __restrict__ shift) {
  int d = blockIdx.x;
  int tid = threadIdx.x;
  __shared__ float ls[256], ls2[256];
  ls[tid] = rawxsum[tid * D_DIM + d];
  ls2[tid] = rawxsq[tid * D_DIM + d];
  __syncthreads();
  for (int off = 128; off; off >>= 1) {
    if (tid < off) {
      ls[tid] += ls[tid + off];
      ls2[tid] += ls2[tid + off];
    }
    __syncthreads();
  }
  if (tid == 0) {
    float mu = ls[0] * (1.0f / N_NODES);
    float var = ls2[0] * (1.0f / N_NODES) - mu * mu;
    float rstd = rsqrtf(var + BN_EPS);
    float sc = gamma[d] * rstd;
    scale[d] = sc;
    shift[d] = beta[d] - mu * sc;
  }
}

// ---- L4: wave per node: deg from own bin, dis = rsqrt(deg+1), y = bf16(dis*xhat) ----
__global__ void __launch_bounds__(256) make_y(const float* __restrict__ x,
                                              const float* __restrict__ scale,
                                              const float* __restrict__ shift,
                                              const int* __restrict__ cursor,
                                              const unsigned* __restrict__ csr,
                                              float* __restrict__ dis,
                                              __hip_bfloat162* __restrict__ y) {
  int n = blockIdx.x * 4 + (threadIdx.x >> 6);
  int lane = threadIdx.x & 63;
  int c = min(cursor[n], BINCAP);
  unsigned rec = (lane < c) ? csr[n * BINCAP + lane] : 0u;
  float s = waveReduceSum(bf_lo(rec));  // low 16 bits = bf16 ew; rec=0 -> 0.0
  float dv = s + 1.0f;                  // + self-loop weight
  float dn = dv > 0.f ? rsqrtf(fmaxf(dv, 1e-12f)) : 0.f;
  if (lane == 0) dis[n] = dn;
  float2 scv = ((const float2*)scale)[lane];
  float2 shv = ((const float2*)shift)[lane];
  float2 xv = ((const float2*)x)[n * 64 + lane];
  float2 yv;
  yv.x = dn * (xv.x * scv.x + shv.x);
  yv.y = dn * (xv.y * scv.y + shv.y);
  y[n * 64 + lane] = __float22bfloat162_rn(yv);
}

// ---- L5: wave per node: agg[n] = bf16( dis[n]*(y[n] + sum_e ew_e*y[src_e]) ) ----
__global__ void __launch_bounds__(256) node_gather(const __hip_bfloat162* __restrict__ y,
                                                   const float* __restrict__ dis,
                                                   const int* __restrict__ cursor,
                                                   const unsigned* __restrict__ csr,
                                                   __hip_bfloat162* __restrict__ agg) {
  int n = blockIdx.x * 4 + (threadIdx.x >> 6);
  int lane = threadIdx.x & 63;
  int c = min(cursor[n], BINCAP);
  const uint4* bin4 = (const uint4*)(csr + n * BINCAP);  // 16B-aligned (192B bins)
  float2 a = __bfloat1622float2(y[n * 64 + lane]);       // self term
  int j = 0;
  for (; j + 4 <= c; j += 4) {
    uint4 r4 = bin4[j >> 2];
    float2 v0 = __bfloat1622float2(y[(r4.x >> 16) * 64 + lane]);
    float2 v1 = __bfloat1622float2(y[(r4.y >> 16) * 64 + lane]);
    float2 v2 = __bfloat1622float2(y[(r4.z >> 16) * 64 + lane]);
    float2 v3 = __bfloat1622float2(y[(r4.w >> 16) * 64 + lane]);
    float w0 = bf_lo(r4.x), w1 = bf_lo(r4.y), w2 = bf_lo(r4.z), w3 = bf_lo(r4.w);
    a.x += w0 * v0.x + w1 * v1.x + w2 * v2.x + w3 * v3.x;
    a.y += w0 * v0.y + w1 * v1.y + w2 * v2.y + w3 * v3.y;
  }
  for (; j < c; j++) {
    unsigned r = csr[n * BINCAP + j];
    float2 v = __bfloat1622float2(y[(r >> 16) * 64 + lane]);
    float w = bf_lo(r);
    a.x += w * v.x;
    a.y += w * v.y;
  }
  float dn = dis[n];
  a.x *= dn;
  a.y *= dn;
  agg[n * 64 + lane] = __float22bfloat162_rn(a);
}

// ---- L6: routing v3 (R7-proven): telescoped wv/bv, global agg reads, LDS softmax ----
__global__ void __launch_bounds__(1024) routing_fused(
    const unsigned* __restrict__ agg_bf, const int* __restrict__ start,
    const float* __restrict__ W, const float* __restrict__ WT, const float* __restrict__ bias,
    const float* __restrict__ rawxsum, const float* __restrict__ scale,
    const float* __restrict__ shift, float* __restrict__ out) {
  int g = blockIdx.x;
  int tid = threadIdx.x;
  int st = start[g], c = start[g + 1] - st;

  __shared__ float dt_sh[MAXC][T_CAPS];
  __shared__ float ac_sh[T_CAPS][D_DIM];
  __shared__ float s_sh[T_CAPS][D_DIM];
  __shared__ float wv_sh[T_CAPS][132];
  __shared__ float csum_sh[T_CAPS], bv_sh[T_CAPS], f_sh[T_CAPS], s2p[T_CAPS][2];
  __shared__ float csp_sh[32];

  float* scratch = &dt_sh[0][0];
  const uint2* aggb2 = (const uint2*)agg_bf;
  const uint4* aggb4 = (const uint4*)agg_bf;

  for (int i = tid; i < T_CAPS * 132; i += 1024) (&wv_sh[0][0])[i] = 0.f;
  if (tid < T_CAPS) {
    bv_sh[tid] = 0.f;
    csum_sh[tid] = 0.125f * (float)c;
  }
  {
    int d2 = tid & 63, h = tid >> 6;
    float sx = 0.f, sy = 0.f;
    for (int n = st + h; n < st + c; n += 16) {
      unsigned u = agg_bf[n * 64 + d2];
      sx += bf_lo(u);
      sy += bf_hi(u);
    }
    scratch[h * 128 + d2 * 2] = sx;
    scratch[h * 128 + d2 * 2 + 1] = sy;
  }
  __syncthreads();
  if (tid < 128) {
    float s = 0.f;
#pragma unroll
    for (int h = 0; h < 16; h++) s += scratch[h * 128 + tid];
    s *= 0.125f;
#pragma unroll
    for (int t = 0; t < T_CAPS; t++) ac_sh[t][tid] = s;
  }
  __syncthreads();

  int tG = tid >> 7, oG = tid & 127;
  int nL = tid >> 3, tL = tid & 7;
  int tA = tid >> 7, rep = (tid >> 5) & 3, l32 = tid & 31;

  for (int iter = 0; iter < 3; iter++) {
    {  // GEMV1
      const float* Wt = W + (tG << 14);
      float s = 0.f;
#pragma unroll 8
      for (int dd = 0; dd < D_DIM; dd++) s += ac_sh[tG][dd] * Wt[dd * D_DIM + oG];
      s += csum_sh[tG] * bias[tG * D_DIM + oG];
      if (iter == 2) {
        float cf = (float)c;
        float ic = 1.0f / fmaxf(cf, 1.0f);
        s += (scale[oG] * rawxsum[g * D_DIM + oG] + cf * shift[oG]) * ic;
      }
      s_sh[tG][oG] = s;
      float p = waveReduceSum(s * s);
      if ((tid & 63) == 0) s2p[tG][(tid >> 6) & 1] = p;
    }
    __syncthreads();
    if (tid < T_CAPS) {
      float s2 = s2p[tid][0] + s2p[tid][1];
      float f = (s2 / (1.0f + s2)) * rsqrtf(s2 + 1e-16f);
      f_sh[tid] = f;
      if (iter == 2) out[g * T_CAPS + tid] = sqrtf(f * f * s2 + 1e-16f);
    }
    __syncthreads();
    if (iter == 2) return;
    s_sh[tG][oG] *= f_sh[tG];
    __syncthreads();
    {  // GEMV2 (running wv/bv)
      const float* WTt = WT + (tG << 14);
      float s = 0.f;
#pragma unroll 8
      for (int oo = 0; oo < D_DIM; oo++) s += s_sh[tG][oo] * WTt[oo * D_DIM + oG];
      wv_sh[tG][oG] += s;
      float bp = bias[tG * D_DIM + oG] * s_sh[tG][oG];
      bp = waveReduceSum(bp);
      if ((tid & 63) == 0) s2p[tG][(tid >> 6) & 1] = bp;
    }
    __syncthreads();
    if (tid < T_CAPS) bv_sh[tid] += s2p[tid][0] + s2p[tid][1];
    __syncthreads();

    float4 acc = make_float4(0.f, 0.f, 0.f, 0.f);
    float cslr = 0.f;
    for (int cb = 0; cb < c; cb += MAXC) {
      int nv = min(MAXC, c - cb);
      for (int n = nL; n < nv; n += 128) {
        const uint4* rowp = aggb4 + (size_t)(st + cb + n) * 16;
        float pr = 0.f;
#pragma unroll 4
        for (int k = 0; k < 16; k++) {
          uint4 u = rowp[k];
          float4 wa = *(const float4*)&wv_sh[tL][k * 8];
          float4 wb = *(const float4*)&wv_sh[tL][k * 8 + 4];
          pr += bf_lo(u.x) * wa.x + bf_hi(u.x) * wa.y + bf_lo(u.y) * wa.z + bf_hi(u.y) * wa.w;
          pr += bf_lo(u.z) * wb.x + bf_hi(u.z) * wb.y + bf_lo(u.w) * wb.z + bf_hi(u.w) * wb.w;
        }
        dt_sh[n][tL] = pr + bv_sh[tL];
      }
      __syncthreads();
      if (tid < nv) {
        float l0 = dt_sh[tid][0], l1 = dt_sh[tid][1], l2 = dt_sh[tid][2], l3 = dt_sh[tid][3];
        float l4 = dt_sh[tid][4], l5 = dt_sh[tid][5], l6 = dt_sh[tid][6], l7 = dt_sh[tid][7];
        float m = fmaxf(fmaxf(fmaxf(l0, l1), fmaxf(l2, l3)),
                        fmaxf(fmaxf(l4, l5), fmaxf(l6, l7)));
        float e0 = __expf(l0 - m), e1 = __expf(l1 - m), e2 = __expf(l2 - m),
              e3 = __expf(l3 - m), e4 = __expf(l4 - m), e5 = __expf(l5 - m),
              e6 = __expf(l6 - m), e7 = __expf(l7 - m);
        float iz = 1.0f / (e0 + e1 + e2 + e3 + e4 + e5 + e6 + e7);
        dt_sh[tid][0] = e0 * iz;
        dt_sh[tid][1] = e1 * iz;
        dt_sh[tid][2] = e2 * iz;
        dt_sh[tid][3] = e3 * iz;
        dt_sh[tid][4] = e4 * iz;
        dt_sh[tid][5] = e5 * iz;
        dt_sh[tid][6] = e6 * iz;
        dt_sh[tid][7] = e7 * iz;
      }
      __syncthreads();
      for (int nj = rep; nj < nv; nj += 4) {
        float cj = dt_sh[nj][tA];
        uint2 u = aggb2[(size_t)(st + cb + nj) * 32 + l32];
        acc.x += cj * bf_lo(u.x);
        acc.y += cj * bf_hi(u.x);
        acc.z += cj * bf_lo(u.y);
        acc.w += cj * bf_hi(u.y);
        if (l32 == 0) cslr += cj;
      }
      __syncthreads();
    }
    int d4 = l32 << 2;
    if (rep > 0) *(float4*)&scratch[(((rep - 1) << 3) + tA) * 128 + d4] = acc;
    if (l32 == 0) csp_sh[tid >> 5] = cslr;
    __syncthreads();
    if (rep == 0) {
#pragma unroll
      for (int m = 0; m < 3; m++) {
        float4 o4 = *(const float4*)&scratch[((m << 3) + tA) * 128 + d4];
        acc.x += o4.x;
        acc.y += o4.y;
        acc.z += o4.z;
        acc.w += o4.w;
      }
      *(float4*)&ac_sh[tA][d4] = acc;
    }
    if (tid < T_CAPS)
      csum_sh[tid] = csp_sh[tid * 4] + csp_sh[tid * 4 + 1] + csp_sh[tid * 4 + 2] +
                     csp_sh[tid * 4 + 3];
    __syncthreads();
  }
}

extern "C" void kernel_launch(void* const* d_in, const int* in_sizes, int n_in, void* d_out,
                              int out_size, void* d_ws, size_t ws_size, hipStream_t stream) {
  const float* x = (const float*)d_in[0];
  const float* ew = (const float*)d_in[1];
  const float* gamma = (const float*)d_in[2];
  const float* beta = (const float*)d_in[3];
  const float* W = (const float*)d_in[4];
  const float* bias = (const float*)d_in[5];
  const int* eidx = (const int*)d_in[6];
  const int* batch = (const int*)d_in[7];
  float* out = (float*)d_out;
  float* w = (float*)d_ws;

  const int* row = eidx;
  const int* col = eidx + N_EDGES;

  int* cursor = (int*)w;                       // N (zeroed in prep; doubles as cnt)
  int* start = cursor + N_NODES;               // 258 (even pad)
  float* scale = (float*)(start + 258);        // 128
  float* shift = scale + 128;                  // 128
  float* dis = shift + 128;                    // N
  float* rawxsum = dis + N_NODES;              // 256*128
  float* rawxsq = rawxsum + N_GRAPHS * D_DIM;  // 256*128
  float* WT = rawxsq + N_GRAPHS * D_DIM;       // 131072
  unsigned* csr = (unsigned*)(WT + T_CAPS * D_DIM * D_DIM);  // N*BINCAP*4B (9.8 MB)
  __hip_bfloat162* y = (__hip_bfloat162*)(csr + (size_t)N_NODES * BINCAP);  // N*64
  unsigned* agg_bf = (unsigned*)(y + (size_t)N_NODES * 64);  // N*64

  prep<<<N_NODES / 256, 256, 0, stream>>>(batch, W, start, cursor, WT);
  fill_x<<<300 + N_GRAPHS, 256, 0, stream>>>(row, col, ew, cursor, csr, x, start, rawxsum,
                                             rawxsq);
  bn_fin<<<D_DIM, 256, 0, stream>>>(rawxsum, rawxsq, gamma, beta, scale, shift);
  make_y<<<N_NODES / 4, 256, 0, stream>>>(x, scale, shift, cursor, csr, dis, y);
  node_gather<<<N_NODES / 4, 256, 0, stream>>>(y, dis, cursor, csr, agg_bf ? (__hip_bfloat162*)agg_bf : nullptr);
  routing_fused<<<N_GRAPHS, 1024, 0, stream>>>(agg_bf, start, W, WT, bias, rawxsum, scale,
                                               shift, out);
}

// Round 12
// 231.780 us; speedup vs baseline: 2.3332x; 1.1030x over previous
//
#include <hip/hip_runtime.h>
#include <hip/hip_bf16.h>
#include <math.h>

#define N_NODES 51200
#define N_EDGES 614400
#define N_GRAPHS 256
#define T_CAPS 8
#define D_DIM 128
#define BN_EPS 1e-5f
#define MAXC 512     // routing chunk size
#define NBUCK 200    // buckets of 256 nodes (col>>8)
#define BCAP 4096    // edges per bucket capacity (mean 3072, sd 55)
#define EPB 2048     // edges per scatter block (256 thr x 8)

__device__ inline float waveReduceSum(float v) {
#pragma unroll
  for (int off = 1; off < 64; off <<= 1) v += __shfl_xor(v, off, 64);
  return v;
}
__device__ inline float bf_lo(unsigned u) { return __uint_as_float(u << 16); }
__device__ inline float bf_hi(unsigned u) { return __uint_as_float(u & 0xffff0000u); }

// ---- L1: zero bucket cursors + graph bounds (sorted batch) + W transpose ----
__global__ void __launch_bounds__(256) prep(const int* __restrict__ batch,
                                            const float* __restrict__ W,
                                            int* __restrict__ start, int* __restrict__ bcur,
                                            float* __restrict__ WT) {
  int i = blockIdx.x * 256 + threadIdx.x;  // 51200 threads
  if (i < NBUCK) bcur[i] = 0;
  int bn = batch[i];
  if (i == 0) {
    for (int g = 0; g <= bn; g++) start[g] = 0;
  } else {
    int bp = batch[i - 1];
    for (int g = bp + 1; g <= bn; g++) start[g] = i;
  }
  if (i == N_NODES - 1)
    for (int g = bn + 1; g <= N_GRAPHS; g++) start[g] = N_NODES;
  for (int j = i; j < T_CAPS * D_DIM * D_DIM; j += N_NODES) {
    int t = j >> 14, r = j & 16383;
    int o = r >> 7, oo = r & 127;
    WT[(t << 14) + (oo << 7) + o] = W[j];
  }
}

// ---- L2: LDS-bucketed edge scatter (blocks 0..299) || per-graph xstats (300..555) ----
// Edge record: x = (col<<16)|src, y = bf16(ew) bits. Grouped writes per bucket.
__global__ void __launch_bounds__(256) scatter_x(
    const int* __restrict__ row, const int* __restrict__ col, const float* __restrict__ ew,
    int* __restrict__ bcur, uint2* __restrict__ ebuck, const float* __restrict__ x,
    const int* __restrict__ start, float* __restrict__ rawxsum, float* __restrict__ rawxsq) {
  int bid = blockIdx.x, tid = threadIdx.x;
  if (bid < 300) {
    __shared__ uint2 staged[EPB];  // 16 KB
    __shared__ int hcnt[256], lbase[256], gbase[256], scant[256];
    unsigned rx[8], ry[8];
    int bk[8], idx[8];
    int e0 = bid * EPB + tid;
#pragma unroll
    for (int k = 0; k < 8; k++) {
      int e = e0 + k * 256;
      int c = col[e];
      unsigned u = __float_as_uint(ew[e]);
      unsigned wb = (u + 0x7FFFu + ((u >> 16) & 1u)) >> 16;  // RNE bf16 bits
      rx[k] = ((unsigned)c << 16) | (unsigned)row[e];
      ry[k] = wb;
      bk[k] = c >> 8;
    }
    hcnt[tid] = 0;
    __syncthreads();
#pragma unroll
    for (int k = 0; k < 8; k++) idx[k] = atomicAdd(&hcnt[bk[k]], 1);
    __syncthreads();
    int v = hcnt[tid];
    scant[tid] = v;
    __syncthreads();
    for (int off = 1; off < 256; off <<= 1) {
      int u = (tid >= off) ? scant[tid - off] : 0;
      __syncthreads();
      scant[tid] += u;
      __syncthreads();
    }
    lbase[tid] = scant[tid] - v;
    __syncthreads();
#pragma unroll
    for (int k = 0; k < 8; k++) staged[lbase[bk[k]] + idx[k]] = make_uint2(rx[k], ry[k]);
    if (tid < NBUCK) gbase[tid] = atomicAdd(&bcur[tid], hcnt[tid]);
    __syncthreads();
    for (int i = tid; i < EPB; i += 256) {
      uint2 r = staged[i];
      int b = r.x >> 24;  // col>>8
      int pos = gbase[b] + (i - lbase[b]);
      if (pos < BCAP) ebuck[b * BCAP + pos] = r;
    }
    return;
  }
  int g = bid - 300;
  __shared__ float ls[256], ls2[256];
  int d = tid & 127, h = tid >> 7;
  int st = start[g], en = start[g + 1];
  float s = 0.f, s2 = 0.f;
  for (int n = st + h; n < en; n += 2) {
    float v = x[n * D_DIM + d];
    s += v;
    s2 += v * v;
  }
  ls[tid] = s;
  ls2[tid] = s2;
  __syncthreads();
  if (h == 0) {
    rawxsum[g * D_DIM + d] = ls[d] + ls[d + 128];
    rawxsq[g * D_DIM + d] = ls2[d] + ls2[d + 128];
  }
}

// ---- L3: BN finalize: one block per feature d ----
__global__ void __launch_bounds__(256) bn_fin(const float* __restrict__ rawxsum,
                                              const float* __restrict__ rawxsq,
                                              const float* __restrict__ gamma,
                                              const float* __restrict__ beta,
                                              float* __restrict__ scale,
                                              float* __restrict__ shift) {
  int d = blockIdx.x;
  int tid = threadIdx.x;
  __shared__ float ls[256], ls2[256];
  ls[tid] = rawxsum[tid * D_DIM + d];
  ls2[tid] = rawxsq[tid * D_DIM + d];
  __syncthreads();
  for (int off = 128; off; off >>= 1) {
    if (tid < off) {
      ls[tid] += ls[tid + off];
      ls2[tid] += ls2[tid + off];
    }
    __syncthreads();
  }
  if (tid == 0) {
    float mu = ls[0] * (1.0f / N_NODES);
    float var = ls2[0] * (1.0f / N_NODES) - mu * mu;
    float rstd = rsqrtf(var + BN_EPS);
    float sc = gamma[d] * rstd;
    scale[d] = sc;
    shift[d] = beta[d] - mu * sc;
  }
}

// ---- L4: per-bucket counting sort -> compact CSR + deg/dis + y (one block/bucket) ----
__global__ void __launch_bounds__(256) build(const uint2* __restrict__ ebuck,
                                             const int* __restrict__ bcur,
                                             unsigned* __restrict__ csr,
                                             int* __restrict__ nstart, int* __restrict__ ncnt,
                                             const float* __restrict__ x,
                                             const float* __restrict__ scale,
                                             const float* __restrict__ shift,
                                             float* __restrict__ dis,
                                             __hip_bfloat162* __restrict__ y) {
  int b = blockIdx.x, tid = threadIdx.x;
  __shared__ uint2 staged[BCAP];   // 32 KB
  __shared__ unsigned outr[BCAP];  // 16 KB
  __shared__ int hist[256], pref[256], cur[256], scant[256];
  __shared__ float dis_l[256];
  int cnt = min(bcur[b], BCAP);
  for (int i = tid; i < cnt; i += 256) staged[i] = ebuck[b * BCAP + i];
  hist[tid] = 0;
  __syncthreads();
  for (int i = tid; i < cnt; i += 256) {
    int dl = (staged[i].x >> 16) & 255;
    atomicAdd(&hist[dl], 1);
  }
  __syncthreads();
  int v = hist[tid];
  scant[tid] = v;
  __syncthreads();
  for (int off = 1; off < 256; off <<= 1) {
    int u = (tid >= off) ? scant[tid - off] : 0;
    __syncthreads();
    scant[tid] += u;
    __syncthreads();
  }
  pref[tid] = scant[tid] - v;
  cur[tid] = pref[tid];
  __syncthreads();
  for (int i = tid; i < cnt; i += 256) {
    uint2 r = staged[i];
    int dl = (r.x >> 16) & 255;
    int p = atomicAdd(&cur[dl], 1);
    outr[p] = ((r.x & 0xFFFFu) << 16) | r.y;  // (src:16 | bf16(ew):16)
  }
  __syncthreads();
  for (int i = tid; i < cnt; i += 256) csr[b * BCAP + i] = outr[i];
  int n = b * 256 + tid;
  int p0 = pref[tid], hc = hist[tid];
  nstart[n] = b * BCAP + p0;
  ncnt[n] = hc;
  float s = 0.f;
  for (int j = p0; j < p0 + hc; j++) s += bf_lo(outr[j]);
  float dv = s + 1.0f;  // + self-loop weight
  float dn = dv > 0.f ? rsqrtf(fmaxf(dv, 1e-12f)) : 0.f;
  dis[n] = dn;
  dis_l[tid] = dn;
  __syncthreads();
  const float2* x2 = (const float2*)x;
  const float2* sc2 = (const float2*)scale;
  const float2* sh2 = (const float2*)shift;
  for (int i = tid; i < 256 * 64; i += 256) {
    int nl = i >> 6, l = i & 63;
    float dnl = dis_l[nl];
    float2 scv = sc2[l], shv = sh2[l];
    float2 xv = x2[(b * 256 + nl) * 64 + l];
    float2 yv;
    yv.x = dnl * (xv.x * scv.x + shv.x);
    yv.y = dnl * (xv.y * scv.y + shv.y);
    y[(b * 256 + nl) * 64 + l] = __float22bfloat162_rn(yv);
  }
}

// ---- L5: wave per node: agg[n] = bf16( dis[n]*(y[n] + sum_e ew_e*y[src_e]) ) ----
__global__ void __launch_bounds__(256) node_gather(const __hip_bfloat162* __restrict__ y,
                                                   const float* __restrict__ dis,
                                                   const int* __restrict__ nstart,
                                                   const int* __restrict__ ncnt,
                                                   const unsigned* __restrict__ csr,
                                                   __hip_bfloat162* __restrict__ agg) {
  int n = blockIdx.x * 4 + (threadIdx.x >> 6);
  int lane = threadIdx.x & 63;
  int st = nstart[n], c = ncnt[n];
  float2 a = __bfloat1622float2(y[n * 64 + lane]);  // self term
  int j = 0;
  for (; j + 4 <= c; j += 4) {
    unsigned r0 = csr[st + j], r1 = csr[st + j + 1], r2 = csr[st + j + 2],
             r3 = csr[st + j + 3];
    float2 v0 = __bfloat1622float2(y[(r0 >> 16) * 64 + lane]);
    float2 v1 = __bfloat1622float2(y[(r1 >> 16) * 64 + lane]);
    float2 v2 = __bfloat1622float2(y[(r2 >> 16) * 64 + lane]);
    float2 v3 = __bfloat1622float2(y[(r3 >> 16) * 64 + lane]);
    float w0 = bf_lo(r0), w1 = bf_lo(r1), w2 = bf_lo(r2), w3 = bf_lo(r3);
    a.x += w0 * v0.x + w1 * v1.x + w2 * v2.x + w3 * v3.x;
    a.y += w0 * v0.y + w1 * v1.y + w2 * v2.y + w3 * v3.y;
  }
  for (; j < c; j++) {
    unsigned r = csr[st + j];
    float2 v = __bfloat1622float2(y[(r >> 16) * 64 + lane]);
    float w = bf_lo(r);
    a.x += w * v.x;
    a.y += w * v.y;
  }
  float dn = dis[n];
  a.x *= dn;
  a.y *= dn;
  agg[n * 64 + lane] = __float22bfloat162_rn(a);
}

// ---- L6: routing v3 (R7-proven): telescoped wv/bv, global agg reads, LDS softmax ----
__global__ void __launch_bounds__(1024) routing_fused(
    const unsigned* __restrict__ agg_bf, const int* __restrict__ start,
    const float* __restrict__ W, const float* __restrict__ WT, const float* __restrict__ bias,
    const float* __restrict__ rawxsum, const float* __restrict__ scale,
    const float* __restrict__ shift, float* __restrict__ out) {
  int g = blockIdx.x;
  int tid = threadIdx.x;
  int st = start[g], c = start[g + 1] - st;

  __shared__ float dt_sh[MAXC][T_CAPS];
  __shared__ float ac_sh[T_CAPS][D_DIM];
  __shared__ float s_sh[T_CAPS][D_DIM];
  __shared__ float wv_sh[T_CAPS][132];
  __shared__ float csum_sh[T_CAPS], bv_sh[T_CAPS], f_sh[T_CAPS], s2p[T_CAPS][2];
  __shared__ float csp_sh[32];

  float* scratch = &dt_sh[0][0];
  const uint2* aggb2 = (const uint2*)agg_bf;
  const uint4* aggb4 = (const uint4*)agg_bf;

  for (int i = tid; i < T_CAPS * 132; i += 1024) (&wv_sh[0][0])[i] = 0.f;
  if (tid < T_CAPS) {
    bv_sh[tid] = 0.f;
    csum_sh[tid] = 0.125f * (float)c;
  }
  {
    int d2 = tid & 63, h = tid >> 6;
    float sx = 0.f, sy = 0.f;
    for (int n = st + h; n < st + c; n += 16) {
      unsigned u = agg_bf[n * 64 + d2];
      sx += bf_lo(u);
      sy += bf_hi(u);
    }
    scratch[h * 128 + d2 * 2] = sx;
    scratch[h * 128 + d2 * 2 + 1] = sy;
  }
  __syncthreads();
  if (tid < 128) {
    float s = 0.f;
#pragma unroll
    for (int h = 0; h < 16; h++) s += scratch[h * 128 + tid];
    s *= 0.125f;
#pragma unroll
    for (int t = 0; t < T_CAPS; t++) ac_sh[t][tid] = s;
  }
  __syncthreads();

  int tG = tid >> 7, oG = tid & 127;
  int nL = tid >> 3, tL = tid & 7;
  int tA = tid >> 7, rep = (tid >> 5) & 3, l32 = tid & 31;

  for (int iter = 0; iter < 3; iter++) {
    {  // GEMV1
      const float* Wt = W + (tG << 14);
      float s = 0.f;
#pragma unroll 8
      for (int dd = 0; dd < D_DIM; dd++) s += ac_sh[tG][dd] * Wt[dd * D_DIM + oG];
      s += csum_sh[tG] * bias[tG * D_DIM + oG];
      if (iter == 2) {
        float cf = (float)c;
        float ic = 1.0f / fmaxf(cf, 1.0f);
        s += (scale[oG] * rawxsum[g * D_DIM + oG] + cf * shift[oG]) * ic;
      }
      s_sh[tG][oG] = s;
      float p = waveReduceSum(s * s);
      if ((tid & 63) == 0) s2p[tG][(tid >> 6) & 1] = p;
    }
    __syncthreads();
    if (tid < T_CAPS) {
      float s2 = s2p[tid][0] + s2p[tid][1];
      float f = (s2 / (1.0f + s2)) * rsqrtf(s2 + 1e-16f);
      f_sh[tid] = f;
      if (iter == 2) out[g * T_CAPS + tid] = sqrtf(f * f * s2 + 1e-16f);
    }
    __syncthreads();
    if (iter == 2) return;
    s_sh[tG][oG] *= f_sh[tG];
    __syncthreads();
    {  // GEMV2 (running wv/bv)
      const float* WTt = WT + (tG << 14);
      float s = 0.f;
#pragma unroll 8
      for (int oo = 0; oo < D_DIM; oo++) s += s_sh[tG][oo] * WTt[oo * D_DIM + oG];
      wv_sh[tG][oG] += s;
      float bp = bias[tG * D_DIM + oG] * s_sh[tG][oG];
      bp = waveReduceSum(bp);
      if ((tid & 63) == 0) s2p[tG][(tid >> 6) & 1] = bp;
    }
    __syncthreads();
    if (tid < T_CAPS) bv_sh[tid] += s2p[tid][0] + s2p[tid][1];
    __syncthreads();

    float4 acc = make_float4(0.f, 0.f, 0.f, 0.f);
    float cslr = 0.f;
    for (int cb = 0; cb < c; cb += MAXC) {
      int nv = min(MAXC, c - cb);
      for (int n = nL; n < nv; n += 128) {
        const uint4* rowp = aggb4 + (size_t)(st + cb + n) * 16;
        float pr = 0.f;
#pragma unroll 4
        for (int k = 0; k < 16; k++) {
          uint4 u = rowp[k];
          float4 wa = *(const float4*)&wv_sh[tL][k * 8];
          float4 wb = *(const float4*)&wv_sh[tL][k * 8 + 4];
          pr += bf_lo(u.x) * wa.x + bf_hi(u.x) * wa.y + bf_lo(u.y) * wa.z + bf_hi(u.y) * wa.w;
          pr += bf_lo(u.z) * wb.x + bf_hi(u.z) * wb.y + bf_lo(u.w) * wb.z + bf_hi(u.w) * wb.w;
        }
        dt_sh[n][tL] = pr + bv_sh[tL];
      }
      __syncthreads();
      if (tid < nv) {
        float l0 = dt_sh[tid][0], l1 = dt_sh[tid][1], l2 = dt_sh[tid][2], l3 = dt_sh[tid][3];
        float l4 = dt_sh[tid][4], l5 = dt_sh[tid][5], l6 = dt_sh[tid][6], l7 = dt_sh[tid][7];
        float m = fmaxf(fmaxf(fmaxf(l0, l1), fmaxf(l2, l3)),
                        fmaxf(fmaxf(l4, l5), fmaxf(l6, l7)));
        float e0 = __expf(l0 - m), e1 = __expf(l1 - m), e2 = __expf(l2 - m),
              e3 = __expf(l3 - m), e4 = __expf(l4 - m), e5 = __expf(l5 - m),
              e6 = __expf(l6 - m), e7 = __expf(l7 - m);
        float iz = 1.0f / (e0 + e1 + e2 + e3 + e4 + e5 + e6 + e7);
        dt_sh[tid][0] = e0 * iz;
        dt_sh[tid][1] = e1 * iz;
        dt_sh[tid][2] = e2 * iz;
        dt_sh[tid][3] = e3 * iz;
        dt_sh[tid][4] = e4 * iz;
        dt_sh[tid][5] = e5 * iz;
        dt_sh[tid][6] = e6 * iz;
        dt_sh[tid][7] = e7 * iz;
      }
      __syncthreads();
      for (int nj = rep; nj < nv; nj += 4) {
        float cj = dt_sh[nj][tA];
        uint2 u = aggb2[(size_t)(st + cb + nj) * 32 + l32];
        acc.x += cj * bf_lo(u.x);
        acc.y += cj * bf_hi(u.x);
        acc.z += cj * bf_lo(u.y);
        acc.w += cj * bf_hi(u.y);
        if (l32 == 0) cslr += cj;
      }
      __syncthreads();
    }
    int d4 = l32 << 2;
    if (rep > 0) *(float4*)&scratch[(((rep - 1) << 3) + tA) * 128 + d4] = acc;
    if (l32 == 0) csp_sh[tid >> 5] = cslr;
    __syncthreads();
    if (rep == 0) {
#pragma unroll
      for (int m = 0; m < 3; m++) {
        float4 o4 = *(const float4*)&scratch[((m << 3) + tA) * 128 + d4];
        acc.x += o4.x;
        acc.y += o4.y;
        acc.z += o4.z;
        acc.w += o4.w;
      }
      *(float4*)&ac_sh[tA][d4] = acc;
    }
    if (tid < T_CAPS)
      csum_sh[tid] = csp_sh[tid * 4] + csp_sh[tid * 4 + 1] + csp_sh[tid * 4 + 2] +
                     csp_sh[tid * 4 + 3];
    __syncthreads();
  }
}

extern "C" void kernel_launch(void* const* d_in, const int* in_sizes, int n_in, void* d_out,
                              int out_size, void* d_ws, size_t ws_size, hipStream_t stream) {
  const float* x = (const float*)d_in[0];
  const float* ew = (const float*)d_in[1];
  const float* gamma = (const float*)d_in[2];
  const float* beta = (const float*)d_in[3];
  const float* W = (const float*)d_in[4];
  const float* bias = (const float*)d_in[5];
  const int* eidx = (const int*)d_in[6];
  const int* batch = (const int*)d_in[7];
  float* out = (float*)d_out;
  float* w = (float*)d_ws;

  const int* row = eidx;
  const int* col = eidx + N_EDGES;

  int* bcur = (int*)w;                         // 256 (200 used; zeroed in prep)
  int* start = bcur + 256;                     // 260 (even pad)
  float* scale = (float*)(start + 260);        // 128
  float* shift = scale + 128;                  // 128
  float* dis = shift + 128;                    // N
  float* rawxsum = dis + N_NODES;              // 256*128
  float* rawxsq = rawxsum + N_GRAPHS * D_DIM;  // 256*128
  float* WT = rawxsq + N_GRAPHS * D_DIM;       // 131072
  int* nstart = (int*)(WT + T_CAPS * D_DIM * D_DIM);  // N
  int* ncnt = nstart + N_NODES;                       // N
  uint2* ebuck = (uint2*)(ncnt + N_NODES);            // NBUCK*BCAP*8B (6.55 MB)
  unsigned* csr = (unsigned*)(ebuck + (size_t)NBUCK * BCAP);  // NBUCK*BCAP*4B
  __hip_bfloat162* y = (__hip_bfloat162*)(csr + (size_t)NBUCK * BCAP);  // N*64
  unsigned* agg_bf = (unsigned*)(y + (size_t)N_NODES * 64);             // N*64

  prep<<<N_NODES / 256, 256, 0, stream>>>(batch, W, start, bcur, WT);
  scatter_x<<<300 + N_GRAPHS, 256, 0, stream>>>(row, col, ew, bcur, ebuck, x, start, rawxsum,
                                                rawxsq);
  bn_fin<<<D_DIM, 256, 0, stream>>>(rawxsum, rawxsq, gamma, beta, scale, shift);
  build<<<NBUCK, 256, 0, stream>>>(ebuck, bcur, csr, nstart, ncnt, x, scale, shift, dis, y);
  node_gather<<<N_NODES / 4, 256, 0, stream>>>(y, dis, nstart, ncnt, csr, agg_bf ? (__hip_bfloat162*)agg_bf : nullptr);
  routing_fused<<<N_GRAPHS, 1024, 0, stream>>>(agg_bf, start, W, WT, bias, rawxsum, scale,
                                               shift, out);
}